// Round 14
// baseline (962.561 us; speedup 1.0000x reference)
//
#include <hip/hip_runtime.h>
#include <math.h>

// Problem constants
#define BB 64
#define SS 2048
#define DD 64
#define EE 64
#define HH 512
#define FF 4
#define NTOK (BB*SS)          // 131072
#define ZELEMS (NTOK*DD)      // 8388608

// packed-weight layout (shorts) in d_ws:
//  [0 .. 1376256)                : MLP W0'/W1/W2' B-frags (4 flows x 344064)
//  [PK2 .. PK2 + 4*24576)        : an_conv Wa/Wc hi+lo B-frags
#define PK2 1376256
#define AN_PER_FLOW 24576         // Wa hi 8192 | Wa lo 8192 | Wc hi 4096 | Wc lo 4096

typedef float f32x4 __attribute__((ext_vector_type(4)));
typedef float f32x2 __attribute__((ext_vector_type(2)));
typedef short s16x8 __attribute__((ext_vector_type(8)));
typedef unsigned int u32x2 __attribute__((ext_vector_type(2)));

// bf16 round-to-nearest-even (bits in a short) -- used in one-shot pack kernels
__device__ __forceinline__ short f2b(float x) {
  unsigned u = __float_as_uint(x);
  u += 0x7fffu + ((u >> 16) & 1u);
  return (short)(u >> 16);
}
__device__ __forceinline__ float b2f(short h) {
  return __uint_as_float(((unsigned)(unsigned short)h) << 16);
}
// packed f32x2 -> bf16x2 in one VALU op (dst.lo = bf16(a), dst.hi = bf16(b))
__device__ __forceinline__ unsigned cvt_pk_bf16(float a, float b) {
  unsigned r;
  asm("v_cvt_pk_bf16_f32 %0, %1, %2" : "=v"(r) : "v"(a), "v"(b));
  return r;
}

// tanh via sigmoid identity: 1 - 2/(exp(2x)+1).  v_exp+v_rcp, ~3e-7 err.
__device__ __forceinline__ float tanh_fast(float x) {
  float e = __expf(2.0f * x);                       // inf for large x is fine
  return 1.0f - 2.0f * __builtin_amdgcn_rcpf(e + 1.0f);
}
// tanh-form GELU: x*sigmoid(1.59577*(x+0.044715x^3)); max |err| ~5e-4
__device__ __forceinline__ float gelu_fast(float x) {
  float u = x * x;
  float p = x * fmaf(0.07135481283f, u, 1.5957691216f);
  float e = __expf(-p);
  return x * __builtin_amdgcn_rcpf(1.0f + e);
}

// ---------------------------------------------------------------------------
// pack_kernel: MLP fp32 weights -> bf16 MFMA B-fragment layout (unchanged).
// Also zeroes ldj.
// ---------------------------------------------------------------------------
__global__ __launch_bounds__(256) void pack_kernel(
    const float* __restrict__ W0, const float* __restrict__ W1,
    const float* __restrict__ W2, short* __restrict__ wp,
    float* __restrict__ ldj)
{
  int gid = blockIdx.x * 256 + threadIdx.x;
  if (gid < BB) ldj[gid] = 0.f;
  int f = gid / 43008;            // 43008 = 672 tiles * 64 lanes
  if (f >= FF) return;
  int rem = gid - f * 43008;
  int tile = rem >> 6, lane = rem & 63;
  int q = lane >> 4, c = lane & 15;
  short out[8];
  short* dst;
  if (tile < 96) {                       // L0: 3 ktiles x 32 ntiles (K=96: z0..31|ext)
    int kt = tile >> 5, nt = tile & 31;
    #pragma unroll
    for (int j = 0; j < 8; j++) {
      int k = kt*32 + q*8 + j;
      int row = (k < 32) ? k : k + 32;   // skip masked-out z rows 32..63
      out[j] = f2b(W0[f*65536 + row*512 + nt*16 + c]);
    }
    dst = wp + f*344064 + (tile*64 + lane)*8;
  } else if (tile < 608) {               // L1: 16 x 32
    int tl = tile - 96;
    int kt = tl >> 5, nt = tl & 31;
    #pragma unroll
    for (int j = 0; j < 8; j++) {
      int k = kt*32 + q*8 + j;
      out[j] = f2b(W1[f*262144 + k*512 + nt*16 + c]);
    }
    dst = wp + f*344064 + 49152 + (tl*64 + lane)*8;
  } else {                               // L2: 16 x 4 (cols 64..127 only)
    int tl = tile - 608;
    int kt = tl >> 2, nt = tl & 3;
    #pragma unroll
    for (int j = 0; j < 8; j++) {
      int k = kt*32 + q*8 + j;
      out[j] = f2b(W2[f*65536 + k*128 + 64 + nt*16 + c]);
    }
    dst = wp + f*344064 + 311296 + (tl*64 + lane)*8;
  }
  *(s16x8*)dst = *(s16x8*)out;
}

// ---------------------------------------------------------------------------
// pack2_kernel: Wa (64x128) and Wc (64x64) -> hi/lo bf16 B-fragments.
// ---------------------------------------------------------------------------
__global__ __launch_bounds__(256) void pack2_kernel(
    const float* __restrict__ Wa, const float* __restrict__ Wc,
    short* __restrict__ wp)
{
  int gid = blockIdx.x * 256 + threadIdx.x;   // 4 * 24 * 64 = 6144 threads
  int f = gid / 1536;
  if (f >= FF) return;
  int rem = gid - f * 1536;
  int u = rem >> 6, lane = rem & 63;
  int q = lane >> 4, c = lane & 15;
  short hi[8], lo[8];
  short* base = wp + PK2 + f*AN_PER_FLOW;
  short* dh; short* dl;
  if (u < 16) {                          // Wa: K=64 (kt 0..1), N=128 (nt 0..7)
    int kt = u >> 3, nt = u & 7;
    #pragma unroll
    for (int j = 0; j < 8; j++) {
      float v = Wa[f*8192 + (kt*32 + q*8 + j)*128 + nt*16 + c];
      hi[j] = f2b(v);
      lo[j] = f2b(v - b2f(hi[j]));
    }
    dh = base + u*512 + lane*8;
    dl = base + 8192 + u*512 + lane*8;
  } else {                               // Wc: K=64, N=64 (nt 0..3)
    int uc = u - 16;
    int kt = uc >> 2, nt = uc & 3;
    #pragma unroll
    for (int j = 0; j < 8; j++) {
      float v = Wc[f*4096 + (kt*32 + q*8 + j)*64 + nt*16 + c];
      hi[j] = f2b(v);
      lo[j] = f2b(v - b2f(hi[j]));
    }
    dh = base + 16384 + uc*512 + lane*8;
    dl = base + 16384 + 4096 + uc*512 + lane*8;
  }
  *(s16x8*)dh = *(s16x8*)hi;
  *(s16x8*)dl = *(s16x8*)lo;
}

// ---------------------------------------------------------------------------
// slogdet: one block (1 wave) per flow; LU w/ partial pivoting in LDS.
// ---------------------------------------------------------------------------
__global__ __launch_bounds__(64) void slogdet_kernel(
    const float* __restrict__ convW, float* __restrict__ ldj)
{
  __shared__ float A[64*65];
  const int f = blockIdx.x;
  const int t = threadIdx.x;
  for (int i = 0; i < 64; i++) A[i*65 + t] = convW[f*4096 + i*64 + t];
  __syncthreads();
  float lad = 0.f;
  for (int k = 0; k < 64; k++) {
    float v = (t >= k) ? fabsf(A[t*65 + k]) : -1.f;
    int p = t;
    #pragma unroll
    for (int off = 32; off; off >>= 1) {
      float ov = __shfl_down(v, off);
      int  op = __shfl_down(p, off);
      if (ov > v) { v = ov; p = op; }
    }
    p = __shfl(p, 0);
    __syncthreads();
    if (p != k) {
      float tmp = A[k*65 + t];
      A[k*65 + t] = A[p*65 + t];
      A[p*65 + t] = tmp;
    }
    __syncthreads();
    float piv = A[k*65 + k];
    lad += logf(fabsf(piv));
    float m = (t > k) ? A[t*65 + k] / piv : 0.f;
    __syncthreads();
    if (t > k) {
      for (int c = k+1; c < 64; c++)
        A[t*65 + c] = fmaf(-m, A[k*65 + c], A[t*65 + c]);
    }
    __syncthreads();
  }
  atomicAdd(&ldj[t], (float)SS * lad);
}

// ---------------------------------------------------------------------------
// flow_kernel: ALL 4 flows fused.  ROUND-14 = round-11 body (known-good,
// 960.6us / flow 830us) with setprio(1) coverage EXTENDED to the an-GEMM,
// conv, and L0 MFMA clusters (round 11 covered only L1/L2 = 74% of MFMAs;
// that was +80us).  launch_bounds STAYS (512,4): rounds 12/13 showed the
// relaxed-cap variants ((512,2)/(512,3)) fail the build/bench pipeline on
// this large fused body -- the 1-block/CU no-spill operating point is
// unreachable via launch_bounds; spill (~414MB WRITE) is accepted as the
// cost of acc[4][4] amortization (round 10 proved two-pass is worse).
// ---------------------------------------------------------------------------
__global__ __launch_bounds__(512, 4) void flow_kernel(
    const float* __restrict__ z_in, float* __restrict__ zout,
    const int* __restrict__ categ, const float* __restrict__ embed,
    const float* __restrict__ ba, const short* __restrict__ wp,
    const float* __restrict__ b0, const float* __restrict__ b1,
    const float* __restrict__ b2, const float* __restrict__ scal,
    float* __restrict__ ldj)
{
  extern __shared__ char smem[];
  float* zf = (float*)smem;                 // [64][64] f32, swizzled, 16KB
  short* hs = (short*)(smem + 16384);       // [64][512] bf16, swizzled, 64KB
  short* ExtH = hs;                         // an-phase aliases inside hs:
  short* ExtL = hs + 4096;                  //   each [64][64] bf16, 8KB
  short* ehp  = hs + 8192;
  short* elp  = hs + 12288;

  const int t    = threadIdx.x;
  const int tok0 = blockIdx.x * 64;
  const int lane = t & 63;
  const int w    = __builtin_amdgcn_readfirstlane(t >> 6);
  const int q    = lane >> 4, c16 = lane & 15;
  const int swz  = (c16 & 7) << 3;   // bf16 64-col swizzle (rows == c16 mod 16)
  const int zswz = (c16 & 7) << 2;   // f32 64-col swizzle
  const f32x4 vzero = {0.f, 0.f, 0.f, 0.f};

  // ---- stage z (once): 64 rows x 64 f32 ----
  #pragma unroll
  for (int it = 0; it < 2; it++) {
    int idx = t + it*512;
    int r = idx >> 4, c4 = (idx & 15) * 4;
    f32x4 v = *(const f32x4*)&z_in[(tok0 + r)*64 + c4];
    *(f32x4*)&zf[r*64 + (c4 ^ ((r & 7) << 2))] = v;
  }

  float lsum = 0.f;

  for (int f = 0; f < FF; f++) {
    const short* base = wp + PK2 + f*AN_PER_FLOW;
    const short* w0p  = wp + f*344064;
    const short* w1p  = w0p + 49152;
    const short* w2p  = w0p + 311296;

    __syncthreads();   // prev flow's hs reads + zf writes complete

    // ---- stage ext = embed[categ] hi/lo into alias buffers ----
    #pragma unroll
    for (int it = 0; it < 2; it++) {
      int idx = t + it*512;                 // 64 rows x 16 groups
      int r = idx >> 4, c4 = (idx & 15) * 4;
      int sw = (r & 7) << 3;
      f32x4 v = *(const f32x4*)&embed[categ[tok0 + r]*64 + c4];
      unsigned h01 = cvt_pk_bf16(v[0], v[1]);
      unsigned h23 = cvt_pk_bf16(v[2], v[3]);
      float r0 = v[0] - __uint_as_float(h01 << 16);
      float r1 = v[1] - __uint_as_float(h01 & 0xffff0000u);
      float r2 = v[2] - __uint_as_float(h23 << 16);
      float r3 = v[3] - __uint_as_float(h23 & 0xffff0000u);
      u32x2 hv = {h01, h23};
      u32x2 lv = {cvt_pk_bf16(r0, r1), cvt_pk_bf16(r2, r3)};
      *(u32x2*)&ExtH[r*64 + (c4 ^ sw)] = hv;
      *(u32x2*)&ExtL[r*64 + (c4 ^ sw)] = lv;
    }
    __syncthreads();

    const int ntb  = w & 3;          // 16-col tile
    const int rowg = w >> 2;         // 32-row group
    const int db   = ntb*16 + q*4;   // this lane's 4-col base

    // ---- actnorm GEMM (swapped): bias aB, scale aS ----
    f32x4 aB[2], aS[2];
    aB[0] = vzero; aB[1] = vzero; aS[0] = vzero; aS[1] = vzero;
    __builtin_amdgcn_s_setprio(1);
    #pragma unroll
    for (int kt = 0; kt < 2; kt++) {
      s16x8 bhB = *(const s16x8*)&base[(kt*8 + ntb)*512 + lane*8];
      s16x8 blB = *(const s16x8*)&base[8192 + (kt*8 + ntb)*512 + lane*8];
      s16x8 bhS = *(const s16x8*)&base[(kt*8 + ntb + 4)*512 + lane*8];
      s16x8 blS = *(const s16x8*)&base[8192 + (kt*8 + ntb + 4)*512 + lane*8];
      #pragma unroll
      for (int r = 0; r < 2; r++) {
        int row = (rowg*2 + r)*16 + c16;
        s16x8 ah = *(const s16x8*)&ExtH[row*64 + ((kt*32 + q*8) ^ swz)];
        s16x8 al = *(const s16x8*)&ExtL[row*64 + ((kt*32 + q*8) ^ swz)];
        aB[r] = __builtin_amdgcn_mfma_f32_16x16x32_bf16(bhB, ah, aB[r], 0,0,0);
        aB[r] = __builtin_amdgcn_mfma_f32_16x16x32_bf16(blB, ah, aB[r], 0,0,0);
        aB[r] = __builtin_amdgcn_mfma_f32_16x16x32_bf16(bhB, al, aB[r], 0,0,0);
        aS[r] = __builtin_amdgcn_mfma_f32_16x16x32_bf16(bhS, ah, aS[r], 0,0,0);
        aS[r] = __builtin_amdgcn_mfma_f32_16x16x32_bf16(blS, ah, aS[r], 0,0,0);
        aS[r] = __builtin_amdgcn_mfma_f32_16x16x32_bf16(bhS, al, aS[r], 0,0,0);
      }
    }
    __builtin_amdgcn_s_setprio(0);

    // ---- epilogue 1: z' = (z + bias)*exp(tanh s); write hi/lo to ehp/elp ----
    {
      f32x4 bB4 = *(const f32x4*)&ba[f*128 + db];
      f32x4 bS4 = *(const f32x4*)&ba[f*128 + 64 + db];
      #pragma unroll
      for (int r = 0; r < 2; r++) {
        int row = (rowg*2 + r)*16 + c16;
        f32x4 zv = *(const f32x4*)&zf[row*64 + (db ^ zswz)];
        float zp[4];
        #pragma unroll
        for (int i = 0; i < 4; i++) {
          float s = tanh_fast(aS[r][i] + bS4[i]);
          lsum += s;
          zp[i] = (zv[i] + aB[r][i] + bB4[i]) * __expf(s);
        }
        unsigned h01 = cvt_pk_bf16(zp[0], zp[1]);
        unsigned h23 = cvt_pk_bf16(zp[2], zp[3]);
        float r0 = zp[0] - __uint_as_float(h01 << 16);
        float r1 = zp[1] - __uint_as_float(h01 & 0xffff0000u);
        float r2 = zp[2] - __uint_as_float(h23 << 16);
        float r3 = zp[3] - __uint_as_float(h23 & 0xffff0000u);
        u32x2 hv = {h01, h23};
        u32x2 lv = {cvt_pk_bf16(r0, r1), cvt_pk_bf16(r2, r3)};
        *(u32x2*)&ehp[row*64 + (db ^ swz)] = hv;
        *(u32x2*)&elp[row*64 + (db ^ swz)] = lv;
      }
    }
    __syncthreads();   // z' hi/lo visible

    // ---- conv GEMM: z'' = z' @ Wc; write z'' to zf ----
    {
      f32x4 ac[2];
      ac[0] = vzero; ac[1] = vzero;
      __builtin_amdgcn_s_setprio(1);
      #pragma unroll
      for (int kt = 0; kt < 2; kt++) {
        s16x8 bh = *(const s16x8*)&base[16384 + (kt*4 + ntb)*512 + lane*8];
        s16x8 bl = *(const s16x8*)&base[16384 + 4096 + (kt*4 + ntb)*512 + lane*8];
        #pragma unroll
        for (int r = 0; r < 2; r++) {
          int row = (rowg*2 + r)*16 + c16;
          s16x8 ah = *(const s16x8*)&ehp[row*64 + ((kt*32 + q*8) ^ swz)];
          s16x8 al = *(const s16x8*)&elp[row*64 + ((kt*32 + q*8) ^ swz)];
          ac[r] = __builtin_amdgcn_mfma_f32_16x16x32_bf16(bh, ah, ac[r], 0,0,0);
          ac[r] = __builtin_amdgcn_mfma_f32_16x16x32_bf16(bl, ah, ac[r], 0,0,0);
          ac[r] = __builtin_amdgcn_mfma_f32_16x16x32_bf16(bh, al, ac[r], 0,0,0);
        }
      }
      __builtin_amdgcn_s_setprio(0);
      #pragma unroll
      for (int r = 0; r < 2; r++) {
        int row = (rowg*2 + r)*16 + c16;
        *(f32x4*)&zf[row*64 + (db ^ zswz)] = ac[r];
      }
    }
    __syncthreads();   // z'' visible for MLP L0

    f32x4 acc[4][4];

    // ---- MLP L0: (64 x 96) @ (96 x 512); A: kt0 from zf, kt1/2 from ExtH ----
    #pragma unroll
    for (int rt = 0; rt < 4; rt++)
      #pragma unroll
      for (int nl = 0; nl < 4; nl++) acc[rt][nl] = vzero;
    __builtin_amdgcn_s_setprio(1);
    #pragma unroll
    for (int kt = 0; kt < 3; kt++) {
      s16x8 a[4];
      #pragma unroll
      for (int rt = 0; rt < 4; rt++) {
        int row = rt*16 + c16;
        if (kt == 0) {
          f32x4 v0 = *(const f32x4*)&zf[row*64 + ((q*8) ^ zswz)];
          f32x4 v1 = *(const f32x4*)&zf[row*64 + ((q*8 + 4) ^ zswz)];
          union { unsigned u[4]; s16x8 v; } cv;
          cv.u[0] = cvt_pk_bf16(v0[0], v0[1]);
          cv.u[1] = cvt_pk_bf16(v0[2], v0[3]);
          cv.u[2] = cvt_pk_bf16(v1[0], v1[1]);
          cv.u[3] = cvt_pk_bf16(v1[2], v1[3]);
          a[rt] = cv.v;
        } else {
          a[rt] = *(const s16x8*)&ExtH[row*64 + (((kt-1)*32 + q*8) ^ swz)];
        }
      }
      #pragma unroll
      for (int nl = 0; nl < 4; nl++) {
        s16x8 b = *(const s16x8*)&w0p[((kt*32 + w*4 + nl)*64 + lane)*8];
        #pragma unroll
        for (int rt = 0; rt < 4; rt++)
          acc[rt][nl] = __builtin_amdgcn_mfma_f32_16x16x32_bf16(b, a[rt], acc[rt][nl], 0,0,0);
      }
    }
    __builtin_amdgcn_s_setprio(0);
    __syncthreads();   // all reads of zf/ExtH done before hs overwrite
    #pragma unroll
    for (int nl = 0; nl < 4; nl++) {
      int nt = w*4 + nl;
      f32x4 bias = *(const f32x4*)&b0[f*512 + nt*16 + q*4];
      #pragma unroll
      for (int rt = 0; rt < 4; rt++) {
        float g0 = gelu_fast(acc[rt][nl][0] + bias[0]);
        float g1 = gelu_fast(acc[rt][nl][1] + bias[1]);
        float g2 = gelu_fast(acc[rt][nl][2] + bias[2]);
        float g3 = gelu_fast(acc[rt][nl][3] + bias[3]);
        u32x2 pv = {cvt_pk_bf16(g0, g1), cvt_pk_bf16(g2, g3)};
        *(u32x2*)&hs[(rt*16 + c16)*512 + ((nt*16 + q*4) ^ swz)] = pv;
      }
    }
    __syncthreads();

    // ---- MLP L1: (64 x 512) @ (512 x 512), per-nl bn prefetch, setprio ----
    #pragma unroll
    for (int rt = 0; rt < 4; rt++)
      #pragma unroll
      for (int nl = 0; nl < 4; nl++) acc[rt][nl] = vzero;
    {
      s16x8 bcur[4];
      #pragma unroll
      for (int nl = 0; nl < 4; nl++)
        bcur[nl] = *(const s16x8*)&w1p[((w*4 + nl)*64 + lane)*8];
      __builtin_amdgcn_s_setprio(1);
      #pragma unroll 2
      for (int kt = 0; kt < 16; kt++) {
        const int ktn = (kt + 1) & 15;   // wrap: last iter re-loads kt=0 (unused)
        s16x8 a[4];
        #pragma unroll
        for (int rt = 0; rt < 4; rt++)
          a[rt] = *(const s16x8*)&hs[(rt*16 + c16)*512 + ((kt*32 + q*8) ^ swz)];
        #pragma unroll
        for (int nl = 0; nl < 4; nl++) {
          s16x8 bn = *(const s16x8*)&w1p[((ktn*32 + w*4 + nl)*64 + lane)*8];
          #pragma unroll
          for (int rt = 0; rt < 4; rt++)
            acc[rt][nl] = __builtin_amdgcn_mfma_f32_16x16x32_bf16(bcur[nl], a[rt], acc[rt][nl], 0,0,0);
          bcur[nl] = bn;
        }
      }
      __builtin_amdgcn_s_setprio(0);
    }
    __syncthreads();
    #pragma unroll
    for (int nl = 0; nl < 4; nl++) {
      int nt = w*4 + nl;
      f32x4 bias = *(const f32x4*)&b1[f*512 + nt*16 + q*4];
      #pragma unroll
      for (int rt = 0; rt < 4; rt++) {
        float g0 = gelu_fast(acc[rt][nl][0] + bias[0]);
        float g1 = gelu_fast(acc[rt][nl][1] + bias[1]);
        float g2 = gelu_fast(acc[rt][nl][2] + bias[2]);
        float g3 = gelu_fast(acc[rt][nl][3] + bias[3]);
        u32x2 pv = {cvt_pk_bf16(g0, g1), cvt_pk_bf16(g2, g3)};
        *(u32x2*)&hs[(rt*16 + c16)*512 + ((nt*16 + q*4) ^ swz)] = pv;
      }
    }
    __syncthreads();

    // ---- MLP L2: (64 x 512) @ (512 x 64), update zf cols 32..63 ----
    {
      const int ntc = w & 3;
      const int rtb = w >> 2;
      f32x4 a2[2];
      a2[0] = vzero; a2[1] = vzero;
      s16x8 b2cur = *(const s16x8*)&w2p[(ntc*64 + lane)*8];
      __builtin_amdgcn_s_setprio(1);
      #pragma unroll 2
      for (int kt = 0; kt < 16; kt++) {
        const int ktn = (kt + 1) & 15;
        s16x8 b2nxt = *(const s16x8*)&w2p[((ktn*4 + ntc)*64 + lane)*8];
        s16x8 x0 = *(const s16x8*)&hs[(rtb*16 + c16)*512 + ((kt*32 + q*8) ^ swz)];
        s16x8 x1 = *(const s16x8*)&hs[((rtb + 2)*16 + c16)*512 + ((kt*32 + q*8) ^ swz)];
        a2[0] = __builtin_amdgcn_mfma_f32_16x16x32_bf16(b2cur, x0, a2[0], 0,0,0);
        a2[1] = __builtin_amdgcn_mfma_f32_16x16x32_bf16(b2cur, x1, a2[1], 0,0,0);
        b2cur = b2nxt;
      }
      __builtin_amdgcn_s_setprio(0);
      const int ccb = 64 + ntc*16 + q*4;
      f32x4 b2v = *(const f32x4*)&b2[f*128 + ccb];
      const int d0 = ccb >> 1;                 // 32 + ntc*8 + q*2
      f32x2 sc = *(const f32x2*)&scal[f*64 + d0];
      float sf0 = __expf(sc[0]); float mr0 = __builtin_amdgcn_rcpf(fmaxf(sf0, 1.0f));
      float sf1 = __expf(sc[1]); float mr1 = __builtin_amdgcn_rcpf(fmaxf(sf1, 1.0f));
      #pragma unroll
      for (int u = 0; u < 2; u++) {
        int row = (rtb + u*2)*16 + c16;
        int zi = row*64 + (d0 ^ zswz);
        f32x2 zv = *(f32x2*)&zf[zi];
        float s0 = tanh_fast((a2[u][0] + b2v[0]) * mr0) * sf0;
        float s1 = tanh_fast((a2[u][2] + b2v[2]) * mr1) * sf1;
        zv[0] = (zv[0] + (a2[u][1] + b2v[1])) * __expf(s0);
        zv[1] = (zv[1] + (a2[u][3] + b2v[3])) * __expf(s1);
        *(f32x2*)&zf[zi] = zv;
        lsum += s0 + s1;
      }
    }
  }  // flow loop

  __syncthreads();   // final zf state visible

  // ---- write z out (once) ----
  #pragma unroll
  for (int it = 0; it < 2; it++) {
    int idx = t + it*512;
    int r = idx >> 4, c4 = (idx & 15) * 4;
    f32x4 v = *(const f32x4*)&zf[r*64 + (c4 ^ ((r & 7) << 2))];
    *(f32x4*)&zout[(tok0 + r)*64 + c4] = v;
  }

  // ---- ldj: one atomic per wave for all 4 flows ----
  #pragma unroll
  for (int off = 32; off; off >>= 1) lsum += __shfl_xor(lsum, off);
  if (lane == 0) atomicAdd(&ldj[tok0 >> 11], lsum);
}

// ---------------------------------------------------------------------------
extern "C" void kernel_launch(void* const* d_in, const int* in_sizes, int n_in,
                              void* d_out, int out_size, void* d_ws, size_t ws_size,
                              hipStream_t stream) {
  (void)in_sizes; (void)n_in; (void)out_size; (void)ws_size;
  const float* z_in  = (const float*)d_in[0];
  const int*   categ = (const int*)  d_in[1];
  const float* embed = (const float*)d_in[2];
  const float* Wa    = (const float*)d_in[3];
  const float* ba    = (const float*)d_in[4];
  const float* Wc    = (const float*)d_in[5];
  const float* scal  = (const float*)d_in[6];
  const float* W0    = (const float*)d_in[7];
  const float* b0    = (const float*)d_in[8];
  const float* W1    = (const float*)d_in[9];
  const float* b1    = (const float*)d_in[10];
  const float* W2    = (const float*)d_in[11];
  const float* b2    = (const float*)d_in[12];

  float* zbuf = (float*)d_out;          // final z lives in d_out
  float* ldj  = zbuf + ZELEMS;
  short* wp   = (short*)d_ws;           // ~2.95 MB packed bf16 weights

  hipFuncSetAttribute(reinterpret_cast<const void*>(flow_kernel),
                      hipFuncAttributeMaxDynamicSharedMemorySize, 81920);

  pack_kernel<<<672, 256, 0, stream>>>(W0, W1, W2, wp, ldj);
  pack2_kernel<<<24, 256, 0, stream>>>(Wa, Wc, wp);
  slogdet_kernel<<<4, 64, 0, stream>>>(Wc, ldj);
  flow_kernel<<<NTOK/64, 512, 81920, stream>>>(
      z_in, zbuf, categ, embed, ba, wp, b0, b1, b2, scal, ldj);
}

// Round 15
// 902.650 us; speedup vs baseline: 1.0664x; 1.0664x over previous
//
#include <hip/hip_runtime.h>
#include <math.h>

// Problem constants
#define BB 64
#define SS 2048
#define DD 64
#define EE 64
#define HH 512
#define FF 4
#define NTOK (BB*SS)          // 131072
#define ZELEMS (NTOK*DD)      // 8388608

// packed-weight layout (shorts) in d_ws:
//  [0 .. 1376256)                : MLP W0'/W1/W2' B-frags (4 flows x 344064)
//  [PK2 .. PK2 + 4*24576)        : an_conv Wa/Wc hi+lo B-frags
//  [1474560 .. +8)               : slogdet lad[4] (floats)
#define PK2 1376256
#define AN_PER_FLOW 24576         // Wa hi 8192 | Wa lo 8192 | Wc hi 4096 | Wc lo 4096
#define LAD_OFF 1474560           // shorts offset of lad[4] in ws

typedef float f32x4 __attribute__((ext_vector_type(4)));
typedef float f32x2 __attribute__((ext_vector_type(2)));
typedef short s16x8 __attribute__((ext_vector_type(8)));
typedef unsigned int u32x2 __attribute__((ext_vector_type(2)));

// bf16 round-to-nearest-even (bits in a short) -- used in setup packing
__device__ __forceinline__ short f2b(float x) {
  unsigned u = __float_as_uint(x);
  u += 0x7fffu + ((u >> 16) & 1u);
  return (short)(u >> 16);
}
__device__ __forceinline__ float b2f(short h) {
  return __uint_as_float(((unsigned)(unsigned short)h) << 16);
}
// packed f32x2 -> bf16x2 in one VALU op (dst.lo = bf16(a), dst.hi = bf16(b))
__device__ __forceinline__ unsigned cvt_pk_bf16(float a, float b) {
  unsigned r;
  asm("v_cvt_pk_bf16_f32 %0, %1, %2" : "=v"(r) : "v"(a), "v"(b));
  return r;
}

// tanh via sigmoid identity: 1 - 2/(exp(2x)+1).  v_exp+v_rcp, ~3e-7 err.
__device__ __forceinline__ float tanh_fast(float x) {
  float e = __expf(2.0f * x);                       // inf for large x is fine
  return 1.0f - 2.0f * __builtin_amdgcn_rcpf(e + 1.0f);
}
// tanh-form GELU: x*sigmoid(1.59577*(x+0.044715x^3)); max |err| ~5e-4
__device__ __forceinline__ float gelu_fast(float x) {
  float u = x * x;
  float p = x * fmaf(0.07135481283f, u, 1.5957691216f);
  float e = __expf(-p);
  return x * __builtin_amdgcn_rcpf(1.0f + e);
}

// ---------------------------------------------------------------------------
// setup_kernel: pack + pack2 + slogdet MERGED into one dispatch (they were
// 3 serialized launches = ~136us of the 962us total; they are mutually
// independent).  Blocks 0..671: MLP weight pack (+ ldj zero in block 0);
// blocks 672..695: Wa/Wc hi/lo pack; blocks 696..699: slogdet -> lad[4] in
// ws (NOT ldj -- avoids the zero-then-add ordering hazard inside one
// kernel; flow_kernel folds SS*sum(lad) into its ldj atomic).
// slogdet elimination parallelized over all 256 threads (4 column stripes
// per row; cols <= k and row k are read-only during iteration k).
// ---------------------------------------------------------------------------
__global__ __launch_bounds__(256) void setup_kernel(
    const float* __restrict__ W0, const float* __restrict__ W1,
    const float* __restrict__ W2, const float* __restrict__ Wa,
    const float* __restrict__ Wc, short* __restrict__ wp,
    float* __restrict__ ldj)
{
  __shared__ float A[64*65];
  __shared__ int s_p;
  const int tt = threadIdx.x;
  const int blk = blockIdx.x;

  if (blk < 672) {
    // ---- MLP weight pack ----
    int gid = blk * 256 + tt;
    if (gid < BB) ldj[gid] = 0.f;
    int f = gid / 43008;            // 43008 = 672 tiles * 64 lanes
    if (f >= FF) return;
    int rem = gid - f * 43008;
    int tile = rem >> 6, lane = rem & 63;
    int q = lane >> 4, c = lane & 15;
    short out[8];
    short* dst;
    if (tile < 96) {                       // L0: 3 ktiles x 32 ntiles (K=96)
      int kt = tile >> 5, nt = tile & 31;
      #pragma unroll
      for (int j = 0; j < 8; j++) {
        int k = kt*32 + q*8 + j;
        int row = (k < 32) ? k : k + 32;   // skip masked-out z rows 32..63
        out[j] = f2b(W0[f*65536 + row*512 + nt*16 + c]);
      }
      dst = wp + f*344064 + (tile*64 + lane)*8;
    } else if (tile < 608) {               // L1: 16 x 32
      int tl = tile - 96;
      int kt = tl >> 5, nt = tl & 31;
      #pragma unroll
      for (int j = 0; j < 8; j++) {
        int k = kt*32 + q*8 + j;
        out[j] = f2b(W1[f*262144 + k*512 + nt*16 + c]);
      }
      dst = wp + f*344064 + 49152 + (tl*64 + lane)*8;
    } else {                               // L2: 16 x 4 (cols 64..127 only)
      int tl = tile - 608;
      int kt = tl >> 2, nt = tl & 3;
      #pragma unroll
      for (int j = 0; j < 8; j++) {
        int k = kt*32 + q*8 + j;
        out[j] = f2b(W2[f*65536 + k*128 + 64 + nt*16 + c]);
      }
      dst = wp + f*344064 + 311296 + (tl*64 + lane)*8;
    }
    *(s16x8*)dst = *(s16x8*)out;
  } else if (blk < 696) {
    // ---- Wa/Wc hi/lo pack ----
    int gid = (blk - 672) * 256 + tt;     // 24 * 256 = 6144 threads
    int f = gid / 1536;
    if (f >= FF) return;
    int rem = gid - f * 1536;
    int u = rem >> 6, lane = rem & 63;
    int q = lane >> 4, c = lane & 15;
    short hi[8], lo[8];
    short* base = wp + PK2 + f*AN_PER_FLOW;
    short* dh; short* dl;
    if (u < 16) {                          // Wa: K=64 (kt 0..1), N=128 (nt 0..7)
      int kt = u >> 3, nt = u & 7;
      #pragma unroll
      for (int j = 0; j < 8; j++) {
        float v = Wa[f*8192 + (kt*32 + q*8 + j)*128 + nt*16 + c];
        hi[j] = f2b(v);
        lo[j] = f2b(v - b2f(hi[j]));
      }
      dh = base + u*512 + lane*8;
      dl = base + 8192 + u*512 + lane*8;
    } else {                               // Wc: K=64, N=64 (nt 0..3)
      int uc = u - 16;
      int kt = uc >> 2, nt = uc & 3;
      #pragma unroll
      for (int j = 0; j < 8; j++) {
        float v = Wc[f*4096 + (kt*32 + q*8 + j)*64 + nt*16 + c];
        hi[j] = f2b(v);
        lo[j] = f2b(v - b2f(hi[j]));
      }
      dh = base + 16384 + uc*512 + lane*8;
      dl = base + 16384 + 4096 + uc*512 + lane*8;
    }
    *(s16x8*)dh = *(s16x8*)hi;
    *(s16x8*)dl = *(s16x8*)lo;
  } else {
    // ---- slogdet (flow f), LU w/ partial pivoting, 256-thread elimination ----
    const int f = blk - 696;
    for (int idx = tt; idx < 4096; idx += 256) {
      int r = idx >> 6, c = idx & 63;
      A[r*65 + c] = Wc[f*4096 + r*64 + c];
    }
    float lad = 0.f;
    __syncthreads();
    for (int k = 0; k < 64; k++) {
      if (tt < 64) {                       // pivot search, wave 0
        float v = (tt >= k) ? fabsf(A[tt*65 + k]) : -1.f;
        int p = tt;
        #pragma unroll
        for (int off = 32; off; off >>= 1) {
          float ov = __shfl_down(v, off);
          int  op = __shfl_down(p, off);
          if (ov > v) { v = ov; p = op; }
        }
        if (tt == 0) s_p = p;
      }
      __syncthreads();
      int p = s_p;
      if (p != k && tt < 64) {             // row swap (64 cols, wave 0)
        float tmp = A[k*65 + tt];
        A[k*65 + tt] = A[p*65 + tt];
        A[p*65 + tt] = tmp;
      }
      __syncthreads();
      float piv = A[k*65 + k];
      if (tt == 0) lad += logf(fabsf(piv));
      int r = tt & 63;
      if (r > k) {                         // elimination: 4 col-stripes/row
        float m = A[r*65 + k] / piv;       // col k & row k read-only here
        for (int c = k + 1 + (tt >> 6); c < 64; c += 4)
          A[r*65 + c] = fmaf(-m, A[k*65 + c], A[r*65 + c]);
      }
      __syncthreads();
    }
    if (tt == 0) ((float*)(wp + LAD_OFF))[f] = lad;
  }
}

// ---------------------------------------------------------------------------
// flow_kernel: ALL 4 flows fused (round-14 body, 962.6us total / flow 826us,
// absmax 0.0625).  Only change: the designated block per batch (blockIdx&31
// ==0, wave 0) folds SS*sum(lad[0..3]) from ws into its ldj atomic (slogdet
// no longer touches ldj directly).  launch_bounds stays (512,4): relaxed
// caps ((512,2)/(512,3)) fail the build pipeline on this body (r12/r13);
// spill (~435MB WRITE) accepted as the cost of acc[4][4] amortization.
// ---------------------------------------------------------------------------
__global__ __launch_bounds__(512, 4) void flow_kernel(
    const float* __restrict__ z_in, float* __restrict__ zout,
    const int* __restrict__ categ, const float* __restrict__ embed,
    const float* __restrict__ ba, const short* __restrict__ wp,
    const float* __restrict__ b0, const float* __restrict__ b1,
    const float* __restrict__ b2, const float* __restrict__ scal,
    float* __restrict__ ldj)
{
  extern __shared__ char smem[];
  float* zf = (float*)smem;                 // [64][64] f32, swizzled, 16KB
  short* hs = (short*)(smem + 16384);       // [64][512] bf16, swizzled, 64KB
  short* ExtH = hs;                         // an-phase aliases inside hs:
  short* ExtL = hs + 4096;                  //   each [64][64] bf16, 8KB
  short* ehp  = hs + 8192;
  short* elp  = hs + 12288;

  const int t    = threadIdx.x;
  const int tok0 = blockIdx.x * 64;
  const int lane = t & 63;
  const int w    = __builtin_amdgcn_readfirstlane(t >> 6);
  const int q    = lane >> 4, c16 = lane & 15;
  const int swz  = (c16 & 7) << 3;   // bf16 64-col swizzle (rows == c16 mod 16)
  const int zswz = (c16 & 7) << 2;   // f32 64-col swizzle
  const f32x4 vzero = {0.f, 0.f, 0.f, 0.f};

  // ---- stage z (once): 64 rows x 64 f32 ----
  #pragma unroll
  for (int it = 0; it < 2; it++) {
    int idx = t + it*512;
    int r = idx >> 4, c4 = (idx & 15) * 4;
    f32x4 v = *(const f32x4*)&z_in[(tok0 + r)*64 + c4];
    *(f32x4*)&zf[r*64 + (c4 ^ ((r & 7) << 2))] = v;
  }

  float lsum = 0.f;

  for (int f = 0; f < FF; f++) {
    const short* base = wp + PK2 + f*AN_PER_FLOW;
    const short* w0p  = wp + f*344064;
    const short* w1p  = w0p + 49152;
    const short* w2p  = w0p + 311296;

    __syncthreads();   // prev flow's hs reads + zf writes complete

    // ---- stage ext = embed[categ] hi/lo into alias buffers ----
    #pragma unroll
    for (int it = 0; it < 2; it++) {
      int idx = t + it*512;                 // 64 rows x 16 groups
      int r = idx >> 4, c4 = (idx & 15) * 4;
      int sw = (r & 7) << 3;
      f32x4 v = *(const f32x4*)&embed[categ[tok0 + r]*64 + c4];
      unsigned h01 = cvt_pk_bf16(v[0], v[1]);
      unsigned h23 = cvt_pk_bf16(v[2], v[3]);
      float r0 = v[0] - __uint_as_float(h01 << 16);
      float r1 = v[1] - __uint_as_float(h01 & 0xffff0000u);
      float r2 = v[2] - __uint_as_float(h23 << 16);
      float r3 = v[3] - __uint_as_float(h23 & 0xffff0000u);
      u32x2 hv = {h01, h23};
      u32x2 lv = {cvt_pk_bf16(r0, r1), cvt_pk_bf16(r2, r3)};
      *(u32x2*)&ExtH[r*64 + (c4 ^ sw)] = hv;
      *(u32x2*)&ExtL[r*64 + (c4 ^ sw)] = lv;
    }
    __syncthreads();

    const int ntb  = w & 3;          // 16-col tile
    const int rowg = w >> 2;         // 32-row group
    const int db   = ntb*16 + q*4;   // this lane's 4-col base

    // ---- actnorm GEMM (swapped): bias aB, scale aS ----
    f32x4 aB[2], aS[2];
    aB[0] = vzero; aB[1] = vzero; aS[0] = vzero; aS[1] = vzero;
    __builtin_amdgcn_s_setprio(1);
    #pragma unroll
    for (int kt = 0; kt < 2; kt++) {
      s16x8 bhB = *(const s16x8*)&base[(kt*8 + ntb)*512 + lane*8];
      s16x8 blB = *(const s16x8*)&base[8192 + (kt*8 + ntb)*512 + lane*8];
      s16x8 bhS = *(const s16x8*)&base[(kt*8 + ntb + 4)*512 + lane*8];
      s16x8 blS = *(const s16x8*)&base[8192 + (kt*8 + ntb + 4)*512 + lane*8];
      #pragma unroll
      for (int r = 0; r < 2; r++) {
        int row = (rowg*2 + r)*16 + c16;
        s16x8 ah = *(const s16x8*)&ExtH[row*64 + ((kt*32 + q*8) ^ swz)];
        s16x8 al = *(const s16x8*)&ExtL[row*64 + ((kt*32 + q*8) ^ swz)];
        aB[r] = __builtin_amdgcn_mfma_f32_16x16x32_bf16(bhB, ah, aB[r], 0,0,0);
        aB[r] = __builtin_amdgcn_mfma_f32_16x16x32_bf16(blB, ah, aB[r], 0,0,0);
        aB[r] = __builtin_amdgcn_mfma_f32_16x16x32_bf16(bhB, al, aB[r], 0,0,0);
        aS[r] = __builtin_amdgcn_mfma_f32_16x16x32_bf16(bhS, ah, aS[r], 0,0,0);
        aS[r] = __builtin_amdgcn_mfma_f32_16x16x32_bf16(blS, ah, aS[r], 0,0,0);
        aS[r] = __builtin_amdgcn_mfma_f32_16x16x32_bf16(bhS, al, aS[r], 0,0,0);
      }
    }
    __builtin_amdgcn_s_setprio(0);

    // ---- epilogue 1: z' = (z + bias)*exp(tanh s); write hi/lo to ehp/elp ----
    {
      f32x4 bB4 = *(const f32x4*)&ba[f*128 + db];
      f32x4 bS4 = *(const f32x4*)&ba[f*128 + 64 + db];
      #pragma unroll
      for (int r = 0; r < 2; r++) {
        int row = (rowg*2 + r)*16 + c16;
        f32x4 zv = *(const f32x4*)&zf[row*64 + (db ^ zswz)];
        float zp[4];
        #pragma unroll
        for (int i = 0; i < 4; i++) {
          float s = tanh_fast(aS[r][i] + bS4[i]);
          lsum += s;
          zp[i] = (zv[i] + aB[r][i] + bB4[i]) * __expf(s);
        }
        unsigned h01 = cvt_pk_bf16(zp[0], zp[1]);
        unsigned h23 = cvt_pk_bf16(zp[2], zp[3]);
        float r0 = zp[0] - __uint_as_float(h01 << 16);
        float r1 = zp[1] - __uint_as_float(h01 & 0xffff0000u);
        float r2 = zp[2] - __uint_as_float(h23 << 16);
        float r3 = zp[3] - __uint_as_float(h23 & 0xffff0000u);
        u32x2 hv = {h01, h23};
        u32x2 lv = {cvt_pk_bf16(r0, r1), cvt_pk_bf16(r2, r3)};
        *(u32x2*)&ehp[row*64 + (db ^ swz)] = hv;
        *(u32x2*)&elp[row*64 + (db ^ swz)] = lv;
      }
    }
    __syncthreads();   // z' hi/lo visible

    // ---- conv GEMM: z'' = z' @ Wc; write z'' to zf ----
    {
      f32x4 ac[2];
      ac[0] = vzero; ac[1] = vzero;
      __builtin_amdgcn_s_setprio(1);
      #pragma unroll
      for (int kt = 0; kt < 2; kt++) {
        s16x8 bh = *(const s16x8*)&base[16384 + (kt*4 + ntb)*512 + lane*8];
        s16x8 bl = *(const s16x8*)&base[16384 + 4096 + (kt*4 + ntb)*512 + lane*8];
        #pragma unroll
        for (int r = 0; r < 2; r++) {
          int row = (rowg*2 + r)*16 + c16;
          s16x8 ah = *(const s16x8*)&ehp[row*64 + ((kt*32 + q*8) ^ swz)];
          s16x8 al = *(const s16x8*)&elp[row*64 + ((kt*32 + q*8) ^ swz)];
          ac[r] = __builtin_amdgcn_mfma_f32_16x16x32_bf16(bh, ah, ac[r], 0,0,0);
          ac[r] = __builtin_amdgcn_mfma_f32_16x16x32_bf16(bl, ah, ac[r], 0,0,0);
          ac[r] = __builtin_amdgcn_mfma_f32_16x16x32_bf16(bh, al, ac[r], 0,0,0);
        }
      }
      __builtin_amdgcn_s_setprio(0);
      #pragma unroll
      for (int r = 0; r < 2; r++) {
        int row = (rowg*2 + r)*16 + c16;
        *(f32x4*)&zf[row*64 + (db ^ zswz)] = ac[r];
      }
    }
    __syncthreads();   // z'' visible for MLP L0

    f32x4 acc[4][4];

    // ---- MLP L0: (64 x 96) @ (96 x 512); A: kt0 from zf, kt1/2 from ExtH ----
    #pragma unroll
    for (int rt = 0; rt < 4; rt++)
      #pragma unroll
      for (int nl = 0; nl < 4; nl++) acc[rt][nl] = vzero;
    __builtin_amdgcn_s_setprio(1);
    #pragma unroll
    for (int kt = 0; kt < 3; kt++) {
      s16x8 a[4];
      #pragma unroll
      for (int rt = 0; rt < 4; rt++) {
        int row = rt*16 + c16;
        if (kt == 0) {
          f32x4 v0 = *(const f32x4*)&zf[row*64 + ((q*8) ^ zswz)];
          f32x4 v1 = *(const f32x4*)&zf[row*64 + ((q*8 + 4) ^ zswz)];
          union { unsigned u[4]; s16x8 v; } cv;
          cv.u[0] = cvt_pk_bf16(v0[0], v0[1]);
          cv.u[1] = cvt_pk_bf16(v0[2], v0[3]);
          cv.u[2] = cvt_pk_bf16(v1[0], v1[1]);
          cv.u[3] = cvt_pk_bf16(v1[2], v1[3]);
          a[rt] = cv.v;
        } else {
          a[rt] = *(const s16x8*)&ExtH[row*64 + (((kt-1)*32 + q*8) ^ swz)];
        }
      }
      #pragma unroll
      for (int nl = 0; nl < 4; nl++) {
        s16x8 b = *(const s16x8*)&w0p[((kt*32 + w*4 + nl)*64 + lane)*8];
        #pragma unroll
        for (int rt = 0; rt < 4; rt++)
          acc[rt][nl] = __builtin_amdgcn_mfma_f32_16x16x32_bf16(b, a[rt], acc[rt][nl], 0,0,0);
      }
    }
    __builtin_amdgcn_s_setprio(0);
    __syncthreads();   // all reads of zf/ExtH done before hs overwrite
    #pragma unroll
    for (int nl = 0; nl < 4; nl++) {
      int nt = w*4 + nl;
      f32x4 bias = *(const f32x4*)&b0[f*512 + nt*16 + q*4];
      #pragma unroll
      for (int rt = 0; rt < 4; rt++) {
        float g0 = gelu_fast(acc[rt][nl][0] + bias[0]);
        float g1 = gelu_fast(acc[rt][nl][1] + bias[1]);
        float g2 = gelu_fast(acc[rt][nl][2] + bias[2]);
        float g3 = gelu_fast(acc[rt][nl][3] + bias[3]);
        u32x2 pv = {cvt_pk_bf16(g0, g1), cvt_pk_bf16(g2, g3)};
        *(u32x2*)&hs[(rt*16 + c16)*512 + ((nt*16 + q*4) ^ swz)] = pv;
      }
    }
    __syncthreads();

    // ---- MLP L1: (64 x 512) @ (512 x 512), per-nl bn prefetch, setprio ----
    #pragma unroll
    for (int rt = 0; rt < 4; rt++)
      #pragma unroll
      for (int nl = 0; nl < 4; nl++) acc[rt][nl] = vzero;
    {
      s16x8 bcur[4];
      #pragma unroll
      for (int nl = 0; nl < 4; nl++)
        bcur[nl] = *(const s16x8*)&w1p[((w*4 + nl)*64 + lane)*8];
      __builtin_amdgcn_s_setprio(1);
      #pragma unroll 2
      for (int kt = 0; kt < 16; kt++) {
        const int ktn = (kt + 1) & 15;   // wrap: last iter re-loads kt=0 (unused)
        s16x8 a[4];
        #pragma unroll
        for (int rt = 0; rt < 4; rt++)
          a[rt] = *(const s16x8*)&hs[(rt*16 + c16)*512 + ((kt*32 + q*8) ^ swz)];
        #pragma unroll
        for (int nl = 0; nl < 4; nl++) {
          s16x8 bn = *(const s16x8*)&w1p[((ktn*32 + w*4 + nl)*64 + lane)*8];
          #pragma unroll
          for (int rt = 0; rt < 4; rt++)
            acc[rt][nl] = __builtin_amdgcn_mfma_f32_16x16x32_bf16(bcur[nl], a[rt], acc[rt][nl], 0,0,0);
          bcur[nl] = bn;
        }
      }
      __builtin_amdgcn_s_setprio(0);
    }
    __syncthreads();
    #pragma unroll
    for (int nl = 0; nl < 4; nl++) {
      int nt = w*4 + nl;
      f32x4 bias = *(const f32x4*)&b1[f*512 + nt*16 + q*4];
      #pragma unroll
      for (int rt = 0; rt < 4; rt++) {
        float g0 = gelu_fast(acc[rt][nl][0] + bias[0]);
        float g1 = gelu_fast(acc[rt][nl][1] + bias[1]);
        float g2 = gelu_fast(acc[rt][nl][2] + bias[2]);
        float g3 = gelu_fast(acc[rt][nl][3] + bias[3]);
        u32x2 pv = {cvt_pk_bf16(g0, g1), cvt_pk_bf16(g2, g3)};
        *(u32x2*)&hs[(rt*16 + c16)*512 + ((nt*16 + q*4) ^ swz)] = pv;
      }
    }
    __syncthreads();

    // ---- MLP L2: (64 x 512) @ (512 x 64), update zf cols 32..63 ----
    {
      const int ntc = w & 3;
      const int rtb = w >> 2;
      f32x4 a2[2];
      a2[0] = vzero; a2[1] = vzero;
      s16x8 b2cur = *(const s16x8*)&w2p[(ntc*64 + lane)*8];
      __builtin_amdgcn_s_setprio(1);
      #pragma unroll 2
      for (int kt = 0; kt < 16; kt++) {
        const int ktn = (kt + 1) & 15;
        s16x8 b2nxt = *(const s16x8*)&w2p[((ktn*4 + ntc)*64 + lane)*8];
        s16x8 x0 = *(const s16x8*)&hs[(rtb*16 + c16)*512 + ((kt*32 + q*8) ^ swz)];
        s16x8 x1 = *(const s16x8*)&hs[((rtb + 2)*16 + c16)*512 + ((kt*32 + q*8) ^ swz)];
        a2[0] = __builtin_amdgcn_mfma_f32_16x16x32_bf16(b2cur, x0, a2[0], 0,0,0);
        a2[1] = __builtin_amdgcn_mfma_f32_16x16x32_bf16(b2cur, x1, a2[1], 0,0,0);
        b2cur = b2nxt;
      }
      __builtin_amdgcn_s_setprio(0);
      const int ccb = 64 + ntc*16 + q*4;
      f32x4 b2v = *(const f32x4*)&b2[f*128 + ccb];
      const int d0 = ccb >> 1;                 // 32 + ntc*8 + q*2
      f32x2 sc = *(const f32x2*)&scal[f*64 + d0];
      float sf0 = __expf(sc[0]); float mr0 = __builtin_amdgcn_rcpf(fmaxf(sf0, 1.0f));
      float sf1 = __expf(sc[1]); float mr1 = __builtin_amdgcn_rcpf(fmaxf(sf1, 1.0f));
      #pragma unroll
      for (int u = 0; u < 2; u++) {
        int row = (rtb + u*2)*16 + c16;
        int zi = row*64 + (d0 ^ zswz);
        f32x2 zv = *(f32x2*)&zf[zi];
        float s0 = tanh_fast((a2[u][0] + b2v[0]) * mr0) * sf0;
        float s1 = tanh_fast((a2[u][2] + b2v[2]) * mr1) * sf1;
        zv[0] = (zv[0] + (a2[u][1] + b2v[1])) * __expf(s0);
        zv[1] = (zv[1] + (a2[u][3] + b2v[3])) * __expf(s1);
        *(f32x2*)&zf[zi] = zv;
        lsum += s0 + s1;
      }
    }
  }  // flow loop

  __syncthreads();   // final zf state visible

  // ---- write z out (once) ----
  #pragma unroll
  for (int it = 0; it < 2; it++) {
    int idx = t + it*512;
    int r = idx >> 4, c4 = (idx & 15) * 4;
    f32x4 v = *(const f32x4*)&zf[r*64 + (c4 ^ ((r & 7) << 2))];
    *(f32x4*)&zout[(tok0 + r)*64 + c4] = v;
  }

  // ---- ldj: one atomic per wave; designated block folds slogdet lad ----
  #pragma unroll
  for (int off = 32; off; off >>= 1) lsum += __shfl_xor(lsum, off);
  if (lane == 0) {
    float add = lsum;
    if (w == 0 && (blockIdx.x & 31) == 0) {
      const float* lad4 = (const float*)(wp + LAD_OFF);
      add += (float)SS * (lad4[0] + lad4[1] + lad4[2] + lad4[3]);
    }
    atomicAdd(&ldj[tok0 >> 11], add);
  }
}

// ---------------------------------------------------------------------------
extern "C" void kernel_launch(void* const* d_in, const int* in_sizes, int n_in,
                              void* d_out, int out_size, void* d_ws, size_t ws_size,
                              hipStream_t stream) {
  (void)in_sizes; (void)n_in; (void)out_size; (void)ws_size;
  const float* z_in  = (const float*)d_in[0];
  const int*   categ = (const int*)  d_in[1];
  const float* embed = (const float*)d_in[2];
  const float* Wa    = (const float*)d_in[3];
  const float* ba    = (const float*)d_in[4];
  const float* Wc    = (const float*)d_in[5];
  const float* scal  = (const float*)d_in[6];
  const float* W0    = (const float*)d_in[7];
  const float* b0    = (const float*)d_in[8];
  const float* W1    = (const float*)d_in[9];
  const float* b1    = (const float*)d_in[10];
  const float* W2    = (const float*)d_in[11];
  const float* b2    = (const float*)d_in[12];

  float* zbuf = (float*)d_out;          // final z lives in d_out
  float* ldj  = zbuf + ZELEMS;
  short* wp   = (short*)d_ws;           // ~2.95 MB packed bf16 weights + lad[4]

  hipFuncSetAttribute(reinterpret_cast<const void*>(flow_kernel),
                      hipFuncAttributeMaxDynamicSharedMemorySize, 81920);

  setup_kernel<<<700, 256, 0, stream>>>(W0, W1, W2, Wa, Wc, wp, ldj);
  flow_kernel<<<NTOK/64, 512, 81920, stream>>>(
      z_in, zbuf, categ, embed, ba, wp, b0, b1, b2, scal, ldj);
}

// Round 16
// 855.139 us; speedup vs baseline: 1.1256x; 1.0556x over previous
//
#include <hip/hip_runtime.h>
#include <math.h>

// Problem constants
#define BB 64
#define SS 2048
#define DD 64
#define EE 64
#define HH 512
#define FF 4
#define NTOK (BB*SS)          // 131072
#define ZELEMS (NTOK*DD)      // 8388608

// packed-weight layout (shorts) in d_ws:
//  [0 .. 1376256)                : MLP W0'/W1/W2' B-frags (4 flows x 344064)
//  [PK2 .. PK2 + 4*24576)        : an_conv Wa/Wc hi+lo B-frags
//  [1474560 .. +8)               : slogdet lad[4] (floats)
#define PK2 1376256
#define AN_PER_FLOW 24576         // Wa hi 8192 | Wa lo 8192 | Wc hi 4096 | Wc lo 4096
#define LAD_OFF 1474560           // shorts offset of lad[4] in ws

typedef float f32x4 __attribute__((ext_vector_type(4)));
typedef float f32x2 __attribute__((ext_vector_type(2)));
typedef short s16x8 __attribute__((ext_vector_type(8)));
typedef unsigned int u32x2 __attribute__((ext_vector_type(2)));

// bf16 round-to-nearest-even (bits in a short) -- used in setup packing
__device__ __forceinline__ short f2b(float x) {
  unsigned u = __float_as_uint(x);
  u += 0x7fffu + ((u >> 16) & 1u);
  return (short)(u >> 16);
}
__device__ __forceinline__ float b2f(short h) {
  return __uint_as_float(((unsigned)(unsigned short)h) << 16);
}
// packed f32x2 -> bf16x2 in one VALU op (dst.lo = bf16(a), dst.hi = bf16(b))
__device__ __forceinline__ unsigned cvt_pk_bf16(float a, float b) {
  unsigned r;
  asm("v_cvt_pk_bf16_f32 %0, %1, %2" : "=v"(r) : "v"(a), "v"(b));
  return r;
}

// tanh via sigmoid identity: 1 - 2/(exp(2x)+1).  v_exp+v_rcp, ~3e-7 err.
__device__ __forceinline__ float tanh_fast(float x) {
  float e = __expf(2.0f * x);                       // inf for large x is fine
  return 1.0f - 2.0f * __builtin_amdgcn_rcpf(e + 1.0f);
}
// tanh-form GELU: x*sigmoid(1.59577*(x+0.044715x^3)); max |err| ~5e-4
__device__ __forceinline__ float gelu_fast(float x) {
  float u = x * x;
  float p = x * fmaf(0.07135481283f, u, 1.5957691216f);
  float e = __expf(-p);
  return x * __builtin_amdgcn_rcpf(1.0f + e);
}

// ---------------------------------------------------------------------------
// setup_kernel: pack + pack2 + slogdet merged (round-15 win, ~60us saved).
// Blocks 0..671: MLP weight pack (+ ldj zero); 672..695: Wa/Wc hi/lo pack;
// 696..699: slogdet -> lad[4] in ws (flow_kernel folds SS*sum(lad) in).
// ---------------------------------------------------------------------------
__global__ __launch_bounds__(256) void setup_kernel(
    const float* __restrict__ W0, const float* __restrict__ W1,
    const float* __restrict__ W2, const float* __restrict__ Wa,
    const float* __restrict__ Wc, short* __restrict__ wp,
    float* __restrict__ ldj)
{
  __shared__ float A[64*65];
  __shared__ int s_p;
  const int tt = threadIdx.x;
  const int blk = blockIdx.x;

  if (blk < 672) {
    // ---- MLP weight pack ----
    int gid = blk * 256 + tt;
    if (gid < BB) ldj[gid] = 0.f;
    int f = gid / 43008;            // 43008 = 672 tiles * 64 lanes
    if (f >= FF) return;
    int rem = gid - f * 43008;
    int tile = rem >> 6, lane = rem & 63;
    int q = lane >> 4, c = lane & 15;
    short out[8];
    short* dst;
    if (tile < 96) {                       // L0: 3 ktiles x 32 ntiles (K=96)
      int kt = tile >> 5, nt = tile & 31;
      #pragma unroll
      for (int j = 0; j < 8; j++) {
        int k = kt*32 + q*8 + j;
        int row = (k < 32) ? k : k + 32;   // skip masked-out z rows 32..63
        out[j] = f2b(W0[f*65536 + row*512 + nt*16 + c]);
      }
      dst = wp + f*344064 + (tile*64 + lane)*8;
    } else if (tile < 608) {               // L1: 16 x 32
      int tl = tile - 96;
      int kt = tl >> 5, nt = tl & 31;
      #pragma unroll
      for (int j = 0; j < 8; j++) {
        int k = kt*32 + q*8 + j;
        out[j] = f2b(W1[f*262144 + k*512 + nt*16 + c]);
      }
      dst = wp + f*344064 + 49152 + (tl*64 + lane)*8;
    } else {                               // L2: 16 x 4 (cols 64..127 only)
      int tl = tile - 608;
      int kt = tl >> 2, nt = tl & 3;
      #pragma unroll
      for (int j = 0; j < 8; j++) {
        int k = kt*32 + q*8 + j;
        out[j] = f2b(W2[f*65536 + k*128 + 64 + nt*16 + c]);
      }
      dst = wp + f*344064 + 311296 + (tl*64 + lane)*8;
    }
    *(s16x8*)dst = *(s16x8*)out;
  } else if (blk < 696) {
    // ---- Wa/Wc hi/lo pack ----
    int gid = (blk - 672) * 256 + tt;     // 24 * 256 = 6144 threads
    int f = gid / 1536;
    if (f >= FF) return;
    int rem = gid - f * 1536;
    int u = rem >> 6, lane = rem & 63;
    int q = lane >> 4, c = lane & 15;
    short hi[8], lo[8];
    short* base = wp + PK2 + f*AN_PER_FLOW;
    short* dh; short* dl;
    if (u < 16) {                          // Wa: K=64 (kt 0..1), N=128 (nt 0..7)
      int kt = u >> 3, nt = u & 7;
      #pragma unroll
      for (int j = 0; j < 8; j++) {
        float v = Wa[f*8192 + (kt*32 + q*8 + j)*128 + nt*16 + c];
        hi[j] = f2b(v);
        lo[j] = f2b(v - b2f(hi[j]));
      }
      dh = base + u*512 + lane*8;
      dl = base + 8192 + u*512 + lane*8;
    } else {                               // Wc: K=64, N=64 (nt 0..3)
      int uc = u - 16;
      int kt = uc >> 2, nt = uc & 3;
      #pragma unroll
      for (int j = 0; j < 8; j++) {
        float v = Wc[f*4096 + (kt*32 + q*8 + j)*64 + nt*16 + c];
        hi[j] = f2b(v);
        lo[j] = f2b(v - b2f(hi[j]));
      }
      dh = base + 16384 + uc*512 + lane*8;
      dl = base + 16384 + 4096 + uc*512 + lane*8;
    }
    *(s16x8*)dh = *(s16x8*)hi;
    *(s16x8*)dl = *(s16x8*)lo;
  } else {
    // ---- slogdet (flow f), LU w/ partial pivoting, 256-thread elimination ----
    const int f = blk - 696;
    for (int idx = tt; idx < 4096; idx += 256) {
      int r = idx >> 6, c = idx & 63;
      A[r*65 + c] = Wc[f*4096 + r*64 + c];
    }
    float lad = 0.f;
    __syncthreads();
    for (int k = 0; k < 64; k++) {
      if (tt < 64) {                       // pivot search, wave 0
        float v = (tt >= k) ? fabsf(A[tt*65 + k]) : -1.f;
        int p = tt;
        #pragma unroll
        for (int off = 32; off; off >>= 1) {
          float ov = __shfl_down(v, off);
          int  op = __shfl_down(p, off);
          if (ov > v) { v = ov; p = op; }
        }
        if (tt == 0) s_p = p;
      }
      __syncthreads();
      int p = s_p;
      if (p != k && tt < 64) {             // row swap (64 cols, wave 0)
        float tmp = A[k*65 + tt];
        A[k*65 + tt] = A[p*65 + tt];
        A[p*65 + tt] = tmp;
      }
      __syncthreads();
      float piv = A[k*65 + k];
      if (tt == 0) lad += logf(fabsf(piv));
      int r = tt & 63;
      if (r > k) {                         // elimination: 4 col-stripes/row
        float m = A[r*65 + k] / piv;       // col k & row k read-only here
        for (int c = k + 1 + (tt >> 6); c < 64; c += 4)
          A[r*65 + c] = fmaf(-m, A[k*65 + c], A[r*65 + c]);
      }
      __syncthreads();
    }
    if (tt == 0) ((float*)(wp + LAD_OFF))[f] = lad;
  }
}

// ---------------------------------------------------------------------------
// flow_kernel: ALL 4 flows fused (round-15 pedigree: 902.7us total / flow
// ~825us, absmax 0.0625).  ROUND-16 change: L1 loop reordered to rt-outer /
// nl-inner with a SINGLE live a-fragment + block bnxt[4] prefetch.  Same
// 36-reg b+a state, same 1-iteration prefetch distance, but shorter
// worst-case live-range overlap for the allocator -> marginal spill should
// shrink.  BIT-EXACT: each acc[rt][nl] receives the identical MFMA sequence
// in identical kt order (absmax must stay 0.0625 -- any change = bug).
// launch_bounds stays (512,4): relaxed caps fail the build pipeline (r12/13).
// ---------------------------------------------------------------------------
__global__ __launch_bounds__(512, 4) void flow_kernel(
    const float* __restrict__ z_in, float* __restrict__ zout,
    const int* __restrict__ categ, const float* __restrict__ embed,
    const float* __restrict__ ba, const short* __restrict__ wp,
    const float* __restrict__ b0, const float* __restrict__ b1,
    const float* __restrict__ b2, const float* __restrict__ scal,
    float* __restrict__ ldj)
{
  extern __shared__ char smem[];
  float* zf = (float*)smem;                 // [64][64] f32, swizzled, 16KB
  short* hs = (short*)(smem + 16384);       // [64][512] bf16, swizzled, 64KB
  short* ExtH = hs;                         // an-phase aliases inside hs:
  short* ExtL = hs + 4096;                  //   each [64][64] bf16, 8KB
  short* ehp  = hs + 8192;
  short* elp  = hs + 12288;

  const int t    = threadIdx.x;
  const int tok0 = blockIdx.x * 64;
  const int lane = t & 63;
  const int w    = __builtin_amdgcn_readfirstlane(t >> 6);
  const int q    = lane >> 4, c16 = lane & 15;
  const int swz  = (c16 & 7) << 3;   // bf16 64-col swizzle (rows == c16 mod 16)
  const int zswz = (c16 & 7) << 2;   // f32 64-col swizzle
  const f32x4 vzero = {0.f, 0.f, 0.f, 0.f};

  // ---- stage z (once): 64 rows x 64 f32 ----
  #pragma unroll
  for (int it = 0; it < 2; it++) {
    int idx = t + it*512;
    int r = idx >> 4, c4 = (idx & 15) * 4;
    f32x4 v = *(const f32x4*)&z_in[(tok0 + r)*64 + c4];
    *(f32x4*)&zf[r*64 + (c4 ^ ((r & 7) << 2))] = v;
  }

  float lsum = 0.f;

  for (int f = 0; f < FF; f++) {
    const short* base = wp + PK2 + f*AN_PER_FLOW;
    const short* w0p  = wp + f*344064;
    const short* w1p  = w0p + 49152;
    const short* w2p  = w0p + 311296;

    __syncthreads();   // prev flow's hs reads + zf writes complete

    // ---- stage ext = embed[categ] hi/lo into alias buffers ----
    #pragma unroll
    for (int it = 0; it < 2; it++) {
      int idx = t + it*512;                 // 64 rows x 16 groups
      int r = idx >> 4, c4 = (idx & 15) * 4;
      int sw = (r & 7) << 3;
      f32x4 v = *(const f32x4*)&embed[categ[tok0 + r]*64 + c4];
      unsigned h01 = cvt_pk_bf16(v[0], v[1]);
      unsigned h23 = cvt_pk_bf16(v[2], v[3]);
      float r0 = v[0] - __uint_as_float(h01 << 16);
      float r1 = v[1] - __uint_as_float(h01 & 0xffff0000u);
      float r2 = v[2] - __uint_as_float(h23 << 16);
      float r3 = v[3] - __uint_as_float(h23 & 0xffff0000u);
      u32x2 hv = {h01, h23};
      u32x2 lv = {cvt_pk_bf16(r0, r1), cvt_pk_bf16(r2, r3)};
      *(u32x2*)&ExtH[r*64 + (c4 ^ sw)] = hv;
      *(u32x2*)&ExtL[r*64 + (c4 ^ sw)] = lv;
    }
    __syncthreads();

    const int ntb  = w & 3;          // 16-col tile
    const int rowg = w >> 2;         // 32-row group
    const int db   = ntb*16 + q*4;   // this lane's 4-col base

    // ---- actnorm GEMM (swapped): bias aB, scale aS ----
    f32x4 aB[2], aS[2];
    aB[0] = vzero; aB[1] = vzero; aS[0] = vzero; aS[1] = vzero;
    __builtin_amdgcn_s_setprio(1);
    #pragma unroll
    for (int kt = 0; kt < 2; kt++) {
      s16x8 bhB = *(const s16x8*)&base[(kt*8 + ntb)*512 + lane*8];
      s16x8 blB = *(const s16x8*)&base[8192 + (kt*8 + ntb)*512 + lane*8];
      s16x8 bhS = *(const s16x8*)&base[(kt*8 + ntb + 4)*512 + lane*8];
      s16x8 blS = *(const s16x8*)&base[8192 + (kt*8 + ntb + 4)*512 + lane*8];
      #pragma unroll
      for (int r = 0; r < 2; r++) {
        int row = (rowg*2 + r)*16 + c16;
        s16x8 ah = *(const s16x8*)&ExtH[row*64 + ((kt*32 + q*8) ^ swz)];
        s16x8 al = *(const s16x8*)&ExtL[row*64 + ((kt*32 + q*8) ^ swz)];
        aB[r] = __builtin_amdgcn_mfma_f32_16x16x32_bf16(bhB, ah, aB[r], 0,0,0);
        aB[r] = __builtin_amdgcn_mfma_f32_16x16x32_bf16(blB, ah, aB[r], 0,0,0);
        aB[r] = __builtin_amdgcn_mfma_f32_16x16x32_bf16(bhB, al, aB[r], 0,0,0);
        aS[r] = __builtin_amdgcn_mfma_f32_16x16x32_bf16(bhS, ah, aS[r], 0,0,0);
        aS[r] = __builtin_amdgcn_mfma_f32_16x16x32_bf16(blS, ah, aS[r], 0,0,0);
        aS[r] = __builtin_amdgcn_mfma_f32_16x16x32_bf16(bhS, al, aS[r], 0,0,0);
      }
    }
    __builtin_amdgcn_s_setprio(0);

    // ---- epilogue 1: z' = (z + bias)*exp(tanh s); write hi/lo to ehp/elp ----
    {
      f32x4 bB4 = *(const f32x4*)&ba[f*128 + db];
      f32x4 bS4 = *(const f32x4*)&ba[f*128 + 64 + db];
      #pragma unroll
      for (int r = 0; r < 2; r++) {
        int row = (rowg*2 + r)*16 + c16;
        f32x4 zv = *(const f32x4*)&zf[row*64 + (db ^ zswz)];
        float zp[4];
        #pragma unroll
        for (int i = 0; i < 4; i++) {
          float s = tanh_fast(aS[r][i] + bS4[i]);
          lsum += s;
          zp[i] = (zv[i] + aB[r][i] + bB4[i]) * __expf(s);
        }
        unsigned h01 = cvt_pk_bf16(zp[0], zp[1]);
        unsigned h23 = cvt_pk_bf16(zp[2], zp[3]);
        float r0 = zp[0] - __uint_as_float(h01 << 16);
        float r1 = zp[1] - __uint_as_float(h01 & 0xffff0000u);
        float r2 = zp[2] - __uint_as_float(h23 << 16);
        float r3 = zp[3] - __uint_as_float(h23 & 0xffff0000u);
        u32x2 hv = {h01, h23};
        u32x2 lv = {cvt_pk_bf16(r0, r1), cvt_pk_bf16(r2, r3)};
        *(u32x2*)&ehp[row*64 + (db ^ swz)] = hv;
        *(u32x2*)&elp[row*64 + (db ^ swz)] = lv;
      }
    }
    __syncthreads();   // z' hi/lo visible

    // ---- conv GEMM: z'' = z' @ Wc; write z'' to zf ----
    {
      f32x4 ac[2];
      ac[0] = vzero; ac[1] = vzero;
      __builtin_amdgcn_s_setprio(1);
      #pragma unroll
      for (int kt = 0; kt < 2; kt++) {
        s16x8 bh = *(const s16x8*)&base[16384 + (kt*4 + ntb)*512 + lane*8];
        s16x8 bl = *(const s16x8*)&base[16384 + 4096 + (kt*4 + ntb)*512 + lane*8];
        #pragma unroll
        for (int r = 0; r < 2; r++) {
          int row = (rowg*2 + r)*16 + c16;
          s16x8 ah = *(const s16x8*)&ehp[row*64 + ((kt*32 + q*8) ^ swz)];
          s16x8 al = *(const s16x8*)&elp[row*64 + ((kt*32 + q*8) ^ swz)];
          ac[r] = __builtin_amdgcn_mfma_f32_16x16x32_bf16(bh, ah, ac[r], 0,0,0);
          ac[r] = __builtin_amdgcn_mfma_f32_16x16x32_bf16(bl, ah, ac[r], 0,0,0);
          ac[r] = __builtin_amdgcn_mfma_f32_16x16x32_bf16(bh, al, ac[r], 0,0,0);
        }
      }
      __builtin_amdgcn_s_setprio(0);
      #pragma unroll
      for (int r = 0; r < 2; r++) {
        int row = (rowg*2 + r)*16 + c16;
        *(f32x4*)&zf[row*64 + (db ^ zswz)] = ac[r];
      }
    }
    __syncthreads();   // z'' visible for MLP L0

    f32x4 acc[4][4];

    // ---- MLP L0: (64 x 96) @ (96 x 512); A: kt0 from zf, kt1/2 from ExtH ----
    #pragma unroll
    for (int rt = 0; rt < 4; rt++)
      #pragma unroll
      for (int nl = 0; nl < 4; nl++) acc[rt][nl] = vzero;
    __builtin_amdgcn_s_setprio(1);
    #pragma unroll
    for (int kt = 0; kt < 3; kt++) {
      s16x8 a[4];
      #pragma unroll
      for (int rt = 0; rt < 4; rt++) {
        int row = rt*16 + c16;
        if (kt == 0) {
          f32x4 v0 = *(const f32x4*)&zf[row*64 + ((q*8) ^ zswz)];
          f32x4 v1 = *(const f32x4*)&zf[row*64 + ((q*8 + 4) ^ zswz)];
          union { unsigned u[4]; s16x8 v; } cv;
          cv.u[0] = cvt_pk_bf16(v0[0], v0[1]);
          cv.u[1] = cvt_pk_bf16(v0[2], v0[3]);
          cv.u[2] = cvt_pk_bf16(v1[0], v1[1]);
          cv.u[3] = cvt_pk_bf16(v1[2], v1[3]);
          a[rt] = cv.v;
        } else {
          a[rt] = *(const s16x8*)&ExtH[row*64 + (((kt-1)*32 + q*8) ^ swz)];
        }
      }
      #pragma unroll
      for (int nl = 0; nl < 4; nl++) {
        s16x8 b = *(const s16x8*)&w0p[((kt*32 + w*4 + nl)*64 + lane)*8];
        #pragma unroll
        for (int rt = 0; rt < 4; rt++)
          acc[rt][nl] = __builtin_amdgcn_mfma_f32_16x16x32_bf16(b, a[rt], acc[rt][nl], 0,0,0);
      }
    }
    __builtin_amdgcn_s_setprio(0);
    __syncthreads();   // all reads of zf/ExtH done before hs overwrite
    #pragma unroll
    for (int nl = 0; nl < 4; nl++) {
      int nt = w*4 + nl;
      f32x4 bias = *(const f32x4*)&b0[f*512 + nt*16 + q*4];
      #pragma unroll
      for (int rt = 0; rt < 4; rt++) {
        float g0 = gelu_fast(acc[rt][nl][0] + bias[0]);
        float g1 = gelu_fast(acc[rt][nl][1] + bias[1]);
        float g2 = gelu_fast(acc[rt][nl][2] + bias[2]);
        float g3 = gelu_fast(acc[rt][nl][3] + bias[3]);
        u32x2 pv = {cvt_pk_bf16(g0, g1), cvt_pk_bf16(g2, g3)};
        *(u32x2*)&hs[(rt*16 + c16)*512 + ((nt*16 + q*4) ^ swz)] = pv;
      }
    }
    __syncthreads();

    // ---- MLP L1: (64 x 512) @ (512 x 512) ----
    // rt-outer / nl-inner, single live a-fragment, block bnxt[4] prefetch.
    // Bit-exact vs round 15: per-acc MFMA order over kt is unchanged.
    #pragma unroll
    for (int rt = 0; rt < 4; rt++)
      #pragma unroll
      for (int nl = 0; nl < 4; nl++) acc[rt][nl] = vzero;
    {
      s16x8 bcur[4];
      #pragma unroll
      for (int nl = 0; nl < 4; nl++)
        bcur[nl] = *(const s16x8*)&w1p[((w*4 + nl)*64 + lane)*8];
      __builtin_amdgcn_s_setprio(1);
      #pragma unroll 2
      for (int kt = 0; kt < 16; kt++) {
        const int ktn = (kt + 1) & 15;   // wrap: last iter re-loads kt=0 (unused)
        s16x8 bnxt[4];
        #pragma unroll
        for (int nl = 0; nl < 4; nl++)
          bnxt[nl] = *(const s16x8*)&w1p[((ktn*32 + w*4 + nl)*64 + lane)*8];
        #pragma unroll
        for (int rt = 0; rt < 4; rt++) {
          s16x8 a = *(const s16x8*)&hs[(rt*16 + c16)*512 + ((kt*32 + q*8) ^ swz)];
          #pragma unroll
          for (int nl = 0; nl < 4; nl++)
            acc[rt][nl] = __builtin_amdgcn_mfma_f32_16x16x32_bf16(bcur[nl], a, acc[rt][nl], 0,0,0);
        }
        #pragma unroll
        for (int nl = 0; nl < 4; nl++) bcur[nl] = bnxt[nl];
      }
      __builtin_amdgcn_s_setprio(0);
    }
    __syncthreads();
    #pragma unroll
    for (int nl = 0; nl < 4; nl++) {
      int nt = w*4 + nl;
      f32x4 bias = *(const f32x4*)&b1[f*512 + nt*16 + q*4];
      #pragma unroll
      for (int rt = 0; rt < 4; rt++) {
        float g0 = gelu_fast(acc[rt][nl][0] + bias[0]);
        float g1 = gelu_fast(acc[rt][nl][1] + bias[1]);
        float g2 = gelu_fast(acc[rt][nl][2] + bias[2]);
        float g3 = gelu_fast(acc[rt][nl][3] + bias[3]);
        u32x2 pv = {cvt_pk_bf16(g0, g1), cvt_pk_bf16(g2, g3)};
        *(u32x2*)&hs[(rt*16 + c16)*512 + ((nt*16 + q*4) ^ swz)] = pv;
      }
    }
    __syncthreads();

    // ---- MLP L2: (64 x 512) @ (512 x 64), update zf cols 32..63 ----
    {
      const int ntc = w & 3;
      const int rtb = w >> 2;
      f32x4 a2[2];
      a2[0] = vzero; a2[1] = vzero;
      s16x8 b2cur = *(const s16x8*)&w2p[(ntc*64 + lane)*8];
      __builtin_amdgcn_s_setprio(1);
      #pragma unroll 2
      for (int kt = 0; kt < 16; kt++) {
        const int ktn = (kt + 1) & 15;
        s16x8 b2nxt = *(const s16x8*)&w2p[((ktn*4 + ntc)*64 + lane)*8];
        s16x8 x0 = *(const s16x8*)&hs[(rtb*16 + c16)*512 + ((kt*32 + q*8) ^ swz)];
        s16x8 x1 = *(const s16x8*)&hs[((rtb + 2)*16 + c16)*512 + ((kt*32 + q*8) ^ swz)];
        a2[0] = __builtin_amdgcn_mfma_f32_16x16x32_bf16(b2cur, x0, a2[0], 0,0,0);
        a2[1] = __builtin_amdgcn_mfma_f32_16x16x32_bf16(b2cur, x1, a2[1], 0,0,0);
        b2cur = b2nxt;
      }
      __builtin_amdgcn_s_setprio(0);
      const int ccb = 64 + ntc*16 + q*4;
      f32x4 b2v = *(const f32x4*)&b2[f*128 + ccb];
      const int d0 = ccb >> 1;                 // 32 + ntc*8 + q*2
      f32x2 sc = *(const f32x2*)&scal[f*64 + d0];
      float sf0 = __expf(sc[0]); float mr0 = __builtin_amdgcn_rcpf(fmaxf(sf0, 1.0f));
      float sf1 = __expf(sc[1]); float mr1 = __builtin_amdgcn_rcpf(fmaxf(sf1, 1.0f));
      #pragma unroll
      for (int u = 0; u < 2; u++) {
        int row = (rtb + u*2)*16 + c16;
        int zi = row*64 + (d0 ^ zswz);
        f32x2 zv = *(f32x2*)&zf[zi];
        float s0 = tanh_fast((a2[u][0] + b2v[0]) * mr0) * sf0;
        float s1 = tanh_fast((a2[u][2] + b2v[2]) * mr1) * sf1;
        zv[0] = (zv[0] + (a2[u][1] + b2v[1])) * __expf(s0);
        zv[1] = (zv[1] + (a2[u][3] + b2v[3])) * __expf(s1);
        *(f32x2*)&zf[zi] = zv;
        lsum += s0 + s1;
      }
    }
  }  // flow loop

  __syncthreads();   // final zf state visible

  // ---- write z out (once) ----
  #pragma unroll
  for (int it = 0; it < 2; it++) {
    int idx = t + it*512;
    int r = idx >> 4, c4 = (idx & 15) * 4;
    f32x4 v = *(const f32x4*)&zf[r*64 + (c4 ^ ((r & 7) << 2))];
    *(f32x4*)&zout[(tok0 + r)*64 + c4] = v;
  }

  // ---- ldj: one atomic per wave; designated block folds slogdet lad ----
  #pragma unroll
  for (int off = 32; off; off >>= 1) lsum += __shfl_xor(lsum, off);
  if (lane == 0) {
    float add = lsum;
    if (w == 0 && (blockIdx.x & 31) == 0) {
      const float* lad4 = (const float*)(wp + LAD_OFF);
      add += (float)SS * (lad4[0] + lad4[1] + lad4[2] + lad4[3]);
    }
    atomicAdd(&ldj[tok0 >> 11], add);
  }
}

// ---------------------------------------------------------------------------
extern "C" void kernel_launch(void* const* d_in, const int* in_sizes, int n_in,
                              void* d_out, int out_size, void* d_ws, size_t ws_size,
                              hipStream_t stream) {
  (void)in_sizes; (void)n_in; (void)out_size; (void)ws_size;
  const float* z_in  = (const float*)d_in[0];
  const int*   categ = (const int*)  d_in[1];
  const float* embed = (const float*)d_in[2];
  const float* Wa    = (const float*)d_in[3];
  const float* ba    = (const float*)d_in[4];
  const float* Wc    = (const float*)d_in[5];
  const float* scal  = (const float*)d_in[6];
  const float* W0    = (const float*)d_in[7];
  const float* b0    = (const float*)d_in[8];
  const float* W1    = (const float*)d_in[9];
  const float* b1    = (const float*)d_in[10];
  const float* W2    = (const float*)d_in[11];
  const float* b2    = (const float*)d_in[12];

  float* zbuf = (float*)d_out;          // final z lives in d_out
  float* ldj  = zbuf + ZELEMS;
  short* wp   = (short*)d_ws;           // ~2.95 MB packed bf16 weights + lad[4]

  hipFuncSetAttribute(reinterpret_cast<const void*>(flow_kernel),
                      hipFuncAttributeMaxDynamicSharedMemorySize, 81920);

  setup_kernel<<<700, 256, 0, stream>>>(W0, W1, W2, Wa, Wc, wp, ldj);
  flow_kernel<<<NTOK/64, 512, 81920, stream>>>(
      z_in, zbuf, categ, embed, ba, wp, b0, b1, b2, scal, ldj);
}